// Round 20
// baseline (51.924 us; speedup 1.0000x reference)
//
#include <hip/hip_runtime.h>

typedef unsigned short u16;
typedef __attribute__((ext_vector_type(8))) short bf16x8;  // 8 bf16 = 16 B
typedef __attribute__((ext_vector_type(4))) float f32x4;

constexpr int   kN    = 8192;
constexpr int   kD    = 256;
constexpr float kInvD = 1.0f / 256.0f;
constexpr float kInv2D = 2.0f / 256.0f;   // 2/D
constexpr float kInvN = 1.0f / 8192.0f;

#define GLOAD_LDS16(gptr, ldsptr)                                                   \
  __builtin_amdgcn_global_load_lds(                                                 \
      (const __attribute__((address_space(1))) unsigned int*)(gptr),                \
      (__attribute__((address_space(3))) unsigned int*)(ldsptr), 16, 0, 0)

__device__ __forceinline__ u16 f2bf(float f) {
  union { float f; unsigned u; } c; c.f = f;
  unsigned r = c.u + 0x7fffu + ((c.u >> 16) & 1u);
  return (u16)(r >> 16);
}

// ---------------------------------------------------------------------------
// K1 prep (R14 verbatim): bf16 convert, {sq,id}, out=0. One wave per row.
// ---------------------------------------------------------------------------
__global__ __launch_bounds__(256) void prep_kernel(
    const float* __restrict__ samples, const float* __restrict__ input1,
    u16* __restrict__ bf, float2* __restrict__ sqid, float* __restrict__ out)
{
  const int row  = blockIdx.x * 4 + (threadIdx.x >> 6);
  const int lane = threadIdx.x & 63;
  const float4 v = *(const float4*)(samples + (size_t)row * kD + lane * 4);
  *(ushort4*)(bf + (size_t)row * kD + lane * 4) =
      make_ushort4(f2bf(v.x), f2bf(v.y), f2bf(v.z), f2bf(v.w));
  float ss = v.x * v.x + v.y * v.y + v.z * v.z + v.w * v.w;
#pragma unroll
  for (int m = 32; m >= 1; m >>= 1) ss += __shfl_xor(ss, m);
  if (lane == 0) {
    sqid[row] = make_float2(ss, input1[row * 32 + 7]);  // input1[i,0,F-1]
    out[row]  = 0.0f;
  }
}

// ---------------------------------------------------------------------------
// K2 main: triangle strips, QUAD-BUFFERED slab pipeline, COUNTED vmcnt.
//
// Every prior structure drained vmcnt(0) per barrier (__syncthreads) — the
// measured plateau. Here (guide T4, m218 +38-73%): slab s=(t,kt) -> buffer
// kt (static under kt-unroll); phase = [s_waitcnt vmcnt(8); s_barrier;
// compute buf kt; (kt==3: epilogue); issue slab s+3 -> buf (kt+3)%4].
//  - newest-8 outstanding at any wait = the just-issued stage, so vmcnt(8)
//    retires slab s+... every slab is retired 2 phases after issue and
//    published by the next barrier: ~1600cy to land, drain ~= 0.
//  - issue target buffer was computed >=1 barrier earlier -> no WAR race.
//  - ONE raw s_barrier per phase (vs drain-barrier x2 in R14).
//  - j-side sqid staged to LDS at prologue so the epilogue issues NO vmem
//    loads (compiler can't inject a vmcnt drain for sqjm1/idj).
// 128 KB buffers + 8 KB sqid = 136 KB dynamic LDS -> 1 block/CU; ILP from
// 3-deep in-flight slabs replaces TLP. Grid 256 = one generation.
// Coverage: c = 8h+t in 0..31; d32 pairs in simloss_d32; d>=33 as (b,64-d).
// ---------------------------------------------------------------------------
__global__ __launch_bounds__(256, 1) void simloss_main(
    const u16* __restrict__ bf, const float2* __restrict__ sqid,
    float* __restrict__ out)
{
  extern __shared__ u16 smem[];
  // buffer k (k=0..3): A at k*16384, B at k*16384+8192 (u16 units)
  const float2* sqlds = (const float2*)(smem + 65536);  // [8 tiles][128]

  const int tid  = threadIdx.x;
  const int lane = tid & 63;
  const int w    = tid >> 6;
  const int wm = w >> 1, wn = w & 1, llo = lane & 15, lhi = lane >> 4;

  const int r  = blockIdx.x;   // strip 0..63
  const int h  = blockIdx.y;   // chunk 0..3
  const int i0 = r * 128;

  const int sr = tid >> 3;
  const int sl = tid & 7;

  // stage slab (A from i0, B from jb0, K-seg kt) into buffer bk (literal)
#define STAGE_PAIR(bk, jb0, kt)                                              \
  {                                                                          \
    u16* Ad = smem + (bk) * 16384;                                           \
    u16* Bd = Ad + 8192;                                                     \
    _Pragma("unroll")                                                        \
    for (int cc = 0; cc < 4; ++cc) {                                         \
      const int rr  = cc * 32 + sr;                                          \
      const int ksl = sl ^ (rr & 7);                                         \
      GLOAD_LDS16(bf + (size_t)(i0 + rr) * kD + (kt) * 64 + ksl * 8,         \
                  Ad + rr * 64 + sl * 8);                                    \
      GLOAD_LDS16(bf + (size_t)((jb0) + rr) * kD + (kt) * 64 + ksl * 8,      \
                  Bd + rr * 64 + sl * 8);                                    \
    }                                                                        \
  }

#define COMPUTE_BUF(bk)                                                      \
  {                                                                          \
    const u16* As = smem + (bk) * 16384;                                     \
    const u16* Bs = As + 8192;                                               \
    _Pragma("unroll")                                                        \
    for (int k32 = 0; k32 < 2; ++k32) {                                      \
      bf16x8 a[4], bv[4];                                                    \
      _Pragma("unroll")                                                      \
      for (int mi = 0; mi < 4; ++mi) {                                       \
        const int ra   = wm * 64 + mi * 16 + llo;                            \
        const int slot = (k32 * 4 + lhi) ^ (ra & 7);                         \
        a[mi] = *(const bf16x8*)(As + ra * 64 + slot * 8);                   \
      }                                                                      \
      _Pragma("unroll")                                                      \
      for (int ni = 0; ni < 4; ++ni) {                                       \
        const int rb   = wn * 64 + ni * 16 + llo;                            \
        const int slot = (k32 * 4 + lhi) ^ (rb & 7);                         \
        bv[ni] = *(const bf16x8*)(Bs + rb * 64 + slot * 8);                  \
      }                                                                      \
      __builtin_amdgcn_s_setprio(1);                                         \
      _Pragma("unroll")                                                      \
      for (int mi = 0; mi < 4; ++mi)                                         \
        _Pragma("unroll")                                                    \
        for (int ni = 0; ni < 4; ++ni)                                       \
          acc[mi][ni] = __builtin_amdgcn_mfma_f32_16x16x32_bf16(             \
              a[mi], bv[ni], acc[mi][ni], 0, 0, 0);                          \
      __builtin_amdgcn_s_setprio(0);                                         \
    }                                                                        \
  }

#define WAIT_BAR()                                                           \
  asm volatile("s_waitcnt vmcnt(8)" ::: "memory");                           \
  __builtin_amdgcn_s_barrier();

  // i-side row data (registers, loaded before any staging)
  float sqi_s[4][4], idi[4][4];
#pragma unroll
  for (int mi = 0; mi < 4; ++mi)
#pragma unroll
    for (int rr = 0; rr < 4; ++rr) {
      const float2 p = sqid[i0 + wm * 64 + mi * 16 + lhi * 4 + rr];
      sqi_s[mi][rr] = p.x * kInvD;
      idi[mi][rr]   = p.y;
    }

  // prologue: j-side sqid for all 8 tiles -> LDS (2 x 16B/thread)
#pragma unroll
  for (int it = 0; it < 2; ++it) {
    const int u   = it * 256 + tid;                    // 0..511
    const int tt  = u >> 6;                            // tile 0..7
    const int idx = (u & 63) * 2;                      // row pair
    const int jt0 = ((r + h * 8 + tt) & 63) * 128;
    GLOAD_LDS16((const u16*)(sqid + jt0 + idx), smem + 65536 + u * 8);
  }
  // prologue: slabs (t0,kt0..2) -> buffers 0..2
  {
    const int j0p = ((r + h * 8) & 63) * 128;
    STAGE_PAIR(0, j0p, 0);
    STAGE_PAIR(1, j0p, 1);
    STAGE_PAIR(2, j0p, 2);
  }

  float rowacc[4][4] = {};  // carried across tiles

  for (int t = 0; t < 8; ++t) {
    const int c   = h * 8 + t;                 // tile distance 0..31
    const int j0  = ((r + c) & 63) * 128;
    const int j0n = ((r + c + 1) & 63) * 128;  // next tile (t=7: harmless)

    f32x4 acc[4][4];
#pragma unroll
    for (int mi = 0; mi < 4; ++mi)
#pragma unroll
      for (int ni = 0; ni < 4; ++ni) acc[mi][ni] = {0.f, 0.f, 0.f, 0.f};

    // kt=0: compute buf0 (slab t,0); issue (t,3) -> buf3
    WAIT_BAR();
    COMPUTE_BUF(0);
    STAGE_PAIR(3, j0, 3);
    // kt=1: compute buf1; issue (t+1,0) -> buf0
    WAIT_BAR();
    COMPUTE_BUF(1);
    STAGE_PAIR(0, j0n, 0);
    // kt=2: compute buf2; issue (t+1,1) -> buf1
    WAIT_BAR();
    COMPUTE_BUF(2);
    STAGE_PAIR(1, j0n, 1);
    // kt=3: compute buf3; EPILOGUE (LDS sqid, no vmem loads); issue (t+1,2)
    WAIT_BAR();
    COMPUTE_BUF(3);
    {
      float sqjm1[4], idj[4];
#pragma unroll
      for (int ni = 0; ni < 4; ++ni) {
        const float2 p = sqlds[t * 128 + wn * 64 + ni * 16 + llo];
        sqjm1[ni] = p.x * kInvD - 1.0f;
        idj[ni]   = p.y;
      }
      float colacc[4] = {};
#pragma unroll
      for (int mi = 0; mi < 4; ++mi)
#pragma unroll
        for (int ni = 0; ni < 4; ++ni)
#pragma unroll
          for (int rr = 0; rr < 4; ++rr) {
            float s1 = fmaf(acc[mi][ni][rr], -kInv2D, sqi_s[mi][rr] + sqjm1[ni]);
            s1 += (idi[mi][rr] == idj[ni]) ? 1.0f : 0.0f;
            const float tt2 = s1 * s1;
            rowacc[mi][rr] += tt2;
            colacc[ni] += tt2;
          }
      if (c != 0) {
#pragma unroll
        for (int ni = 0; ni < 4; ++ni) {
          float v = colacc[ni];
          v += __shfl_xor(v, 16);
          v += __shfl_xor(v, 32);
          if (lhi == 0)
            atomicAdd(&out[j0 + wn * 64 + ni * 16 + llo], v * kInvN);
        }
      }
    }
    STAGE_PAIR(2, j0n, 2);
  }

  // block end: row sums (carried across tiles)
#pragma unroll
  for (int mi = 0; mi < 4; ++mi)
#pragma unroll
    for (int rr = 0; rr < 4; ++rr) {
      float v = rowacc[mi][rr];
      v += __shfl_xor(v, 1);
      v += __shfl_xor(v, 2);
      v += __shfl_xor(v, 4);
      v += __shfl_xor(v, 8);
      if (llo == 0)
        atomicAdd(&out[i0 + wm * 64 + mi * 16 + lhi * 4 + rr], v * kInvN);
    }
}

// ---------------------------------------------------------------------------
// K3 d32 (R14 verbatim): the 32 distance-32 tiles, 32 KB static LDS.
// ---------------------------------------------------------------------------
__global__ __launch_bounds__(256, 2) void simloss_d32(
    const u16* __restrict__ bf, const float2* __restrict__ sqid,
    float* __restrict__ out)
{
  __shared__ u16 Abuf[8192];
  __shared__ u16 Bbuf[8192];

  const int tid  = threadIdx.x;
  const int lane = tid & 63;
  const int w    = tid >> 6;
  const int wm = w >> 1, wn = w & 1, llo = lane & 15, lhi = lane >> 4;

  const int i0 = blockIdx.x * 128;
  const int j0 = (blockIdx.x + 32) * 128;
  const int sr = tid >> 3, sl = tid & 7;

  f32x4 acc[4][4];
#pragma unroll
  for (int mi = 0; mi < 4; ++mi)
#pragma unroll
    for (int ni = 0; ni < 4; ++ni) acc[mi][ni] = {0.f, 0.f, 0.f, 0.f};

#pragma unroll
  for (int kt = 0; kt < 4; ++kt) {
#pragma unroll
    for (int cc = 0; cc < 4; ++cc) {
      const int rr  = cc * 32 + sr;
      const int ksl = sl ^ (rr & 7);
      GLOAD_LDS16(bf + (size_t)(i0 + rr) * kD + kt * 64 + ksl * 8, Abuf + rr * 64 + sl * 8);
      GLOAD_LDS16(bf + (size_t)(j0 + rr) * kD + kt * 64 + ksl * 8, Bbuf + rr * 64 + sl * 8);
    }
    __syncthreads();
#pragma unroll
    for (int k32 = 0; k32 < 2; ++k32) {
      bf16x8 a[4], bv[4];
#pragma unroll
      for (int mi = 0; mi < 4; ++mi) {
        const int ra   = wm * 64 + mi * 16 + llo;
        const int slot = (k32 * 4 + lhi) ^ (ra & 7);
        a[mi] = *(const bf16x8*)(Abuf + ra * 64 + slot * 8);
      }
#pragma unroll
      for (int ni = 0; ni < 4; ++ni) {
        const int rb   = wn * 64 + ni * 16 + llo;
        const int slot = (k32 * 4 + lhi) ^ (rb & 7);
        bv[ni] = *(const bf16x8*)(Bbuf + rb * 64 + slot * 8);
      }
      __builtin_amdgcn_s_setprio(1);
#pragma unroll
      for (int mi = 0; mi < 4; ++mi)
#pragma unroll
        for (int ni = 0; ni < 4; ++ni)
          acc[mi][ni] = __builtin_amdgcn_mfma_f32_16x16x32_bf16(
              a[mi], bv[ni], acc[mi][ni], 0, 0, 0);
      __builtin_amdgcn_s_setprio(0);
    }
    __syncthreads();
  }

  float sqi_s[4][4], idi[4][4];
#pragma unroll
  for (int mi = 0; mi < 4; ++mi)
#pragma unroll
    for (int rr = 0; rr < 4; ++rr) {
      const float2 p = sqid[i0 + wm * 64 + mi * 16 + lhi * 4 + rr];
      sqi_s[mi][rr] = p.x * kInvD;
      idi[mi][rr]   = p.y;
    }
  float sqjm1[4], idj[4];
#pragma unroll
  for (int ni = 0; ni < 4; ++ni) {
    const float2 p = sqid[j0 + wn * 64 + ni * 16 + llo];
    sqjm1[ni] = p.x * kInvD - 1.0f;
    idj[ni]   = p.y;
  }

  float rowacc[4][4] = {};
  float colacc[4] = {};
#pragma unroll
  for (int mi = 0; mi < 4; ++mi)
#pragma unroll
    for (int ni = 0; ni < 4; ++ni)
#pragma unroll
      for (int rr = 0; rr < 4; ++rr) {
        float s1 = fmaf(acc[mi][ni][rr], -kInv2D, sqi_s[mi][rr] + sqjm1[ni]);
        s1 += (idi[mi][rr] == idj[ni]) ? 1.0f : 0.0f;
        const float tt = s1 * s1;
        rowacc[mi][rr] += tt;
        colacc[ni] += tt;
      }

#pragma unroll
  for (int mi = 0; mi < 4; ++mi)
#pragma unroll
    for (int rr = 0; rr < 4; ++rr) {
      float v = rowacc[mi][rr];
      v += __shfl_xor(v, 1);
      v += __shfl_xor(v, 2);
      v += __shfl_xor(v, 4);
      v += __shfl_xor(v, 8);
      if (llo == 0)
        atomicAdd(&out[i0 + wm * 64 + mi * 16 + lhi * 4 + rr], v * kInvN);
    }
#pragma unroll
  for (int ni = 0; ni < 4; ++ni) {
    float v = colacc[ni];
    v += __shfl_xor(v, 16);
    v += __shfl_xor(v, 32);
    if (lhi == 0)
      atomicAdd(&out[j0 + wn * 64 + ni * 16 + llo], v * kInvN);
  }
}

// ---------------------------------------------------------------------------
extern "C" void kernel_launch(void* const* d_in, const int* in_sizes, int n_in,
                              void* d_out, int out_size, void* d_ws, size_t ws_size,
                              hipStream_t stream) {
  const float* samples = (const float*)d_in[0];
  const float* input1  = (const float*)d_in[1];
  float* out = (float*)d_out;

  char* ws = (char*)d_ws;
  u16*    bf   = (u16*)ws;                                  // 4 MB bf16 samples
  float2* sqid = (float2*)(ws + (size_t)4 * 1024 * 1024);   // 64 KB {sq, id}

  // 136 KB dynamic LDS: 4 x 32 KB slab buffers + 8 KB j-side sqid
  hipFuncSetAttribute(reinterpret_cast<const void*>(&simloss_main),
                      hipFuncAttributeMaxDynamicSharedMemorySize, 139264);

  prep_kernel<<<kN / 4, 256, 0, stream>>>(samples, input1, bf, sqid, out);
  simloss_main<<<dim3(64, 4), 256, 139264, stream>>>(bf, sqid, out);
  simloss_d32<<<32, 256, 0, stream>>>(bf, sqid, out);
}

// Round 21
// 42.225 us; speedup vs baseline: 1.2297x; 1.2297x over previous
//
#include <hip/hip_runtime.h>

typedef unsigned short u16;
typedef __attribute__((ext_vector_type(8))) short bf16x8;  // 8 bf16 = 16 B
typedef __attribute__((ext_vector_type(4))) float f32x4;

constexpr int   kN    = 8192;
constexpr int   kD    = 256;
constexpr float kInvD = 1.0f / 256.0f;
constexpr float kInv2D = 2.0f / 256.0f;   // 2/D
constexpr float kInvN = 1.0f / 8192.0f;

#define GLOAD_LDS16(gptr, ldsptr)                                                   \
  __builtin_amdgcn_global_load_lds(                                                 \
      (const __attribute__((address_space(1))) unsigned int*)(gptr),                \
      (__attribute__((address_space(3))) unsigned int*)(ldsptr), 16, 0, 0)

__device__ __forceinline__ u16 f2bf(float f) {
  union { float f; unsigned u; } c; c.f = f;
  unsigned r = c.u + 0x7fffu + ((c.u >> 16) & 1u);
  return (u16)(r >> 16);
}

// ---------------------------------------------------------------------------
// K1 prep: bf16 convert, {sq,id}, out=0. 512 blocks x 16 rows (4/wave-iter);
// same per-row work as R14's version, 4x fewer blocks of dispatch spread.
// ---------------------------------------------------------------------------
__global__ __launch_bounds__(256) void prep_kernel(
    const float* __restrict__ samples, const float* __restrict__ input1,
    u16* __restrict__ bf, float2* __restrict__ sqid, float* __restrict__ out)
{
  const int lane = threadIdx.x & 63;
  const int w    = threadIdx.x >> 6;
#pragma unroll
  for (int it = 0; it < 4; ++it) {
    const int row = blockIdx.x * 16 + w * 4 + it;
    const float4 v = *(const float4*)(samples + (size_t)row * kD + lane * 4);
    *(ushort4*)(bf + (size_t)row * kD + lane * 4) =
        make_ushort4(f2bf(v.x), f2bf(v.y), f2bf(v.z), f2bf(v.w));
    float ss = v.x * v.x + v.y * v.y + v.z * v.z + v.w * v.w;
#pragma unroll
    for (int m = 32; m >= 1; m >>= 1) ss += __shfl_xor(ss, m);
    if (lane == 0) {
      sqid[row] = make_float2(ss, input1[row * 32 + 7]);  // input1[i,0,F-1]
      out[row]  = 0.0f;
    }
  }
}

// ---------------------------------------------------------------------------
// K2 main: R14's measured-best body (512 blocks, 2/CU, trip-4 rolled wrapped
// triangle, 2-phase dbuf, XOR swizzle rule #21, carried rowacc) + Phase C:
// blocks 0..31 additionally compute the distance-32 tile {r, r+32} after
// their main loop (block-uniform branch — deletes the simloss_d32 node).
// Graph is now 2 nodes total; R15/R16 showed node count dominates once
// kernels are lean.
// Coverage: c = 4h+t in 0..31 (strip r covers d<=31; d>=33 as (b, 64-d));
// d=32 pairs in Phase C; c=0 diagonal row-sums-only.
// ---------------------------------------------------------------------------
__global__ __launch_bounds__(256, 2) void simloss_main(
    const u16* __restrict__ bf, const float2* __restrict__ sqid,
    float* __restrict__ out)
{
  __shared__ u16 Ab0[8192], Ab1[8192], Bb0[8192], Bb1[8192];  // 4 x 16 KB

  const int bid  = blockIdx.x;     // 0..511
  const int tid  = threadIdx.x;
  const int lane = tid & 63;
  const int w    = tid >> 6;
  const int wm = w >> 1, wn = w & 1, llo = lane & 15, lhi = lane >> 4;

  const int r  = bid & 63;         // strip 0..63
  const int h  = bid >> 6;         // offset chunk 0..7
  const int i0 = r * 128;

  const int sr = tid >> 3;
  const int sl = tid & 7;

#define STAGE_SLAB(dst, grow0, kt)                                          \
  {                                                                         \
    _Pragma("unroll")                                                       \
    for (int cc = 0; cc < 4; ++cc) {                                        \
      const int rr  = cc * 32 + sr;                                         \
      const int ksl = sl ^ (rr & 7);                                        \
      const u16* g  = bf + (size_t)((grow0) + rr) * kD + (kt) * 64 + ksl * 8; \
      GLOAD_LDS16(g, (dst) + rr * 64 + sl * 8);                             \
    }                                                                       \
  }

#define COMPUTE_SLAB(Asrc, Bsrc)                                            \
  {                                                                         \
    _Pragma("unroll")                                                       \
    for (int k32 = 0; k32 < 2; ++k32) {                                     \
      bf16x8 a[4], bv[4];                                                   \
      _Pragma("unroll")                                                     \
      for (int mi = 0; mi < 4; ++mi) {                                      \
        const int ra   = wm * 64 + mi * 16 + llo;                           \
        const int slot = (k32 * 4 + lhi) ^ (ra & 7);                        \
        a[mi] = *(const bf16x8*)((Asrc) + ra * 64 + slot * 8);              \
      }                                                                     \
      _Pragma("unroll")                                                     \
      for (int ni = 0; ni < 4; ++ni) {                                      \
        const int rb   = wn * 64 + ni * 16 + llo;                           \
        const int slot = (k32 * 4 + lhi) ^ (rb & 7);                        \
        bv[ni] = *(const bf16x8*)((Bsrc) + rb * 64 + slot * 8);             \
      }                                                                     \
      __builtin_amdgcn_s_setprio(1);                                        \
      _Pragma("unroll")                                                     \
      for (int mi = 0; mi < 4; ++mi)                                        \
        _Pragma("unroll")                                                   \
        for (int ni = 0; ni < 4; ++ni)                                      \
          acc[mi][ni] = __builtin_amdgcn_mfma_f32_16x16x32_bf16(            \
              a[mi], bv[ni], acc[mi][ni], 0, 0, 0);                         \
      __builtin_amdgcn_s_setprio(0);                                        \
    }                                                                       \
  }

  // i-side row data: block-constant, hoisted
  float sqi_s[4][4], idi[4][4];
#pragma unroll
  for (int mi = 0; mi < 4; ++mi)
#pragma unroll
    for (int rr = 0; rr < 4; ++rr) {
      const float2 p = sqid[i0 + wm * 64 + mi * 16 + lhi * 4 + rr];
      sqi_s[mi][rr] = p.x * kInvD;
      idi[mi][rr]   = p.y;
    }

  float rowacc[4][4] = {};  // carried across tiles

  // prologue: stage (t=0, kt=0) into buf0
  {
    const int j0p = ((r + h * 4) & 63) * 128;
    STAGE_SLAB(Ab0, i0, 0);
    STAGE_SLAB(Bb0, j0p, 0);
  }
  __syncthreads();

  for (int t = 0; t < 4; ++t) {
    const int c   = h * 4 + t;                 // tile distance 0..31
    const int j0  = ((r + c) & 63) * 128;
    const int j0n = ((r + c + 1) & 63) * 128;  // next tile (last: harmless)

    f32x4 acc[4][4];
#pragma unroll
    for (int mi = 0; mi < 4; ++mi)
#pragma unroll
      for (int ni = 0; ni < 4; ++ni) acc[mi][ni] = {0.f, 0.f, 0.f, 0.f};

    // kt=0: prefetch kt1 -> buf1, compute buf0
    STAGE_SLAB(Ab1, i0, 1);
    STAGE_SLAB(Bb1, j0, 1);
    COMPUTE_SLAB(Ab0, Bb0);
    __syncthreads();
    // kt=1: prefetch kt2 -> buf0, compute buf1
    STAGE_SLAB(Ab0, i0, 2);
    STAGE_SLAB(Bb0, j0, 2);
    COMPUTE_SLAB(Ab1, Bb1);
    __syncthreads();
    // kt=2: prefetch kt3 -> buf1, compute buf0
    STAGE_SLAB(Ab1, i0, 3);
    STAGE_SLAB(Bb1, j0, 3);
    COMPUTE_SLAB(Ab0, Bb0);
    __syncthreads();
    // kt=3: prefetch NEXT TILE kt0 -> buf0, compute buf1
    STAGE_SLAB(Ab0, i0, 0);
    STAGE_SLAB(Bb0, j0n, 0);
    COMPUTE_SLAB(Ab1, Bb1);
    __syncthreads();

    // per-tile epilogue
    float sqjm1[4], idj[4];
#pragma unroll
    for (int ni = 0; ni < 4; ++ni) {
      const float2 p = sqid[j0 + wn * 64 + ni * 16 + llo];
      sqjm1[ni] = p.x * kInvD - 1.0f;
      idj[ni]   = p.y;
    }

    float colacc[4] = {};
#pragma unroll
    for (int mi = 0; mi < 4; ++mi)
#pragma unroll
      for (int ni = 0; ni < 4; ++ni)
#pragma unroll
        for (int rr = 0; rr < 4; ++rr) {
          float s1 = fmaf(acc[mi][ni][rr], -kInv2D, sqi_s[mi][rr] + sqjm1[ni]);
          s1 += (idi[mi][rr] == idj[ni]) ? 1.0f : 0.0f;
          const float tt = s1 * s1;
          rowacc[mi][rr] += tt;
          colacc[ni] += tt;
        }

    if (c != 0) {
#pragma unroll
      for (int ni = 0; ni < 4; ++ni) {
        float v = colacc[ni];
        v += __shfl_xor(v, 16);
        v += __shfl_xor(v, 32);
        if (lhi == 0)
          atomicAdd(&out[j0 + wn * 64 + ni * 16 + llo], v * kInvN);
      }
    }
  }

  // row sums (carried across tiles)
#pragma unroll
  for (int mi = 0; mi < 4; ++mi)
#pragma unroll
    for (int rr = 0; rr < 4; ++rr) {
      float v = rowacc[mi][rr];
      v += __shfl_xor(v, 1);
      v += __shfl_xor(v, 2);
      v += __shfl_xor(v, 4);
      v += __shfl_xor(v, 8);
      if (llo == 0)
        atomicAdd(&out[i0 + wm * 64 + mi * 16 + lhi * 4 + rr], v * kInvN);
    }

  // ---- Phase C: distance-32 tile {r, r+32} on blocks 0..31 ----
  if (bid < 32) {
    const int di0 = bid * 128;
    const int dj0 = (bid + 32) * 128;

    f32x4 acc[4][4];
#pragma unroll
    for (int mi = 0; mi < 4; ++mi)
#pragma unroll
      for (int ni = 0; ni < 4; ++ni) acc[mi][ni] = {0.f, 0.f, 0.f, 0.f};

#pragma unroll
    for (int kt = 0; kt < 4; ++kt) {
      STAGE_SLAB(Ab0, di0, kt);
      STAGE_SLAB(Bb0, dj0, kt);
      __syncthreads();
      COMPUTE_SLAB(Ab0, Bb0);
      __syncthreads();
    }

    float dsqi[4][4], didi[4][4];
#pragma unroll
    for (int mi = 0; mi < 4; ++mi)
#pragma unroll
      for (int rr = 0; rr < 4; ++rr) {
        const float2 p = sqid[di0 + wm * 64 + mi * 16 + lhi * 4 + rr];
        dsqi[mi][rr] = p.x * kInvD;
        didi[mi][rr] = p.y;
      }
    float dsqj[4], didj[4];
#pragma unroll
    for (int ni = 0; ni < 4; ++ni) {
      const float2 p = sqid[dj0 + wn * 64 + ni * 16 + llo];
      dsqj[ni] = p.x * kInvD - 1.0f;
      didj[ni] = p.y;
    }

    float drow[4][4] = {};
    float dcol[4] = {};
#pragma unroll
    for (int mi = 0; mi < 4; ++mi)
#pragma unroll
      for (int ni = 0; ni < 4; ++ni)
#pragma unroll
        for (int rr = 0; rr < 4; ++rr) {
          float s1 = fmaf(acc[mi][ni][rr], -kInv2D, dsqi[mi][rr] + dsqj[ni]);
          s1 += (didi[mi][rr] == didj[ni]) ? 1.0f : 0.0f;
          const float tt = s1 * s1;
          drow[mi][rr] += tt;
          dcol[ni] += tt;
        }

#pragma unroll
    for (int mi = 0; mi < 4; ++mi)
#pragma unroll
      for (int rr = 0; rr < 4; ++rr) {
        float v = drow[mi][rr];
        v += __shfl_xor(v, 1);
        v += __shfl_xor(v, 2);
        v += __shfl_xor(v, 4);
        v += __shfl_xor(v, 8);
        if (llo == 0)
          atomicAdd(&out[di0 + wm * 64 + mi * 16 + lhi * 4 + rr], v * kInvN);
      }
#pragma unroll
    for (int ni = 0; ni < 4; ++ni) {
      float v = dcol[ni];
      v += __shfl_xor(v, 16);
      v += __shfl_xor(v, 32);
      if (lhi == 0)
        atomicAdd(&out[dj0 + wn * 64 + ni * 16 + llo], v * kInvN);
    }
  }
}

// ---------------------------------------------------------------------------
extern "C" void kernel_launch(void* const* d_in, const int* in_sizes, int n_in,
                              void* d_out, int out_size, void* d_ws, size_t ws_size,
                              hipStream_t stream) {
  const float* samples = (const float*)d_in[0];
  const float* input1  = (const float*)d_in[1];
  float* out = (float*)d_out;

  char* ws = (char*)d_ws;
  u16*    bf   = (u16*)ws;                                  // 4 MB bf16 samples
  float2* sqid = (float2*)(ws + (size_t)4 * 1024 * 1024);   // 64 KB {sq, id}

  prep_kernel<<<kN / 16, 256, 0, stream>>>(samples, input1, bf, sqid, out);
  simloss_main<<<512, 256, 0, stream>>>(bf, sqid, out);
}